// Round 13
// baseline (2410.429 us; speedup 1.0000x reference)
//
#include <hip/hip_runtime.h>
#include <math.h>

#define D_MODEL 768
#define N_LAYER 8
#define D_INNER 1536
#define D_STATE 16
#define DT_RANK 48
#define D_CONV  4
#define BATCH   4
#define SEQLEN  1024
#define NTOK    (BATCH*SEQLEN)      // 4096 token rows
#define DBC_W   (DT_RANK + 2*D_STATE)  // 80
#define NC      64                  // scan chunks per sequence
#define CHUNK_T (SEQLEN/NC)         // 16 timesteps per chunk
#define XP_KS   16                  // xproj split-K slices
#define XP_KSL  (D_INNER/XP_KS)     // 96 k per slice
#define CONV_TCH 16                 // conv outputs per thread
#define OP_KS   4                   // out_proj split-K slices

typedef __attribute__((ext_vector_type(8))) short short8v;   // 8 bf16 (4 VGPRs)
typedef __attribute__((ext_vector_type(4))) float float4v;   // 4 fp32 acc

// Split fp32 into hi+lo bf16 (both RNE).  x ~= hi + lo, |err| ~ 2^-17 |x|.
__device__ __forceinline__ void split_bf16(float x, short& hi, short& lo) {
  unsigned u = __float_as_uint(x);
  unsigned r = (u + 0x7fffu + ((u >> 16) & 1u)) >> 16;
  hi = (short)r;
  float fhi = __uint_as_float(r << 16);
  float xl = x - fhi;
  unsigned u2 = __float_as_uint(xl);
  unsigned r2 = (u2 + 0x7fffu + ((u2 >> 16) & 1u)) >> 16;
  lo = (short)r2;
}

// Async global->LDS 16B copy: per-lane global src, wave-uniform LDS base;
// lane i's 16B lands at ldsbase + i*16.
__device__ __forceinline__ void gload16(const short* g, short* l) {
  __builtin_amdgcn_global_load_lds(
      (const __attribute__((address_space(1))) void*)g,
      (__attribute__((address_space(3))) void*)l, 16, 0, 0);
}

// ---------------------------------------------------------------------------
// Weight split: fp32 [n] -> bf16 hi[n], lo[n].  n4 = n/4, float4-vectorized.
// Called ONCE per launch for all layers' weights (hoisted out of layer loop).
// ---------------------------------------------------------------------------
__global__ __launch_bounds__(256) void split_kernel(
    const float* __restrict__ src, short* __restrict__ hi,
    short* __restrict__ lo, int n4) {
  int stride = gridDim.x * 256;
  for (int i = blockIdx.x * 256 + threadIdx.x; i < n4; i += stride) {
    float4 v = ((const float4*)src)[i];
    short4 h, g;
    split_bf16(v.x, h.x, g.x);
    split_bf16(v.y, h.y, g.y);
    split_bf16(v.z, h.z, g.z);
    split_bf16(v.w, h.w, g.w);
    ((short4*)hi)[i] = h;
    ((short4*)lo)[i] = g;
  }
}

// ---------------------------------------------------------------------------
// LayerNorm + residual update, with out_proj split-K reduction FUSED.
// float4-vectorized: threads 0..191 each own one float4 of the 768-row.
// first=1: r = x + pos.  first=0: r = resid + sum_k opart[k].
// ---------------------------------------------------------------------------
__global__ __launch_bounds__(256) void ln_kernel(
    const float* __restrict__ x, const float* __restrict__ pos,
    float* __restrict__ resid, const float* __restrict__ opart,
    short* __restrict__ hh_hi, short* __restrict__ hh_lo,
    const float* __restrict__ w, const float* __restrict__ b, int first) {
  int row = blockIdx.x;
  int tid = threadIdx.x;
  size_t base4 = (size_t)row * (D_MODEL / 4);   // float4 index of row start
  __shared__ float red[256];
  __shared__ float s_mu, s_rs;
  float4 v = make_float4(0.f, 0.f, 0.f, 0.f);
  bool act = tid < D_MODEL / 4;                 // 192 active lanes
  if (act) {
    if (first) {
      float4 a = ((const float4*)x)[base4 + tid];
      float4 p = ((const float4*)pos)[base4 + tid];
      v = make_float4(a.x + p.x, a.y + p.y, a.z + p.z, a.w + p.w);
    } else {
      float4 r = ((const float4*)resid)[base4 + tid];
      float4 o = ((const float4*)opart)[base4 + tid];
      float4 s = make_float4(o.x, o.y, o.z, o.w);
#pragma unroll
      for (int k = 1; k < OP_KS; ++k) {
        float4 o2 = ((const float4*)opart)[(size_t)k * (NTOK * D_MODEL / 4) + base4 + tid];
        s.x += o2.x; s.y += o2.y; s.z += o2.z; s.w += o2.w;
      }
      v = make_float4(r.x + s.x, r.y + s.y, r.z + s.z, r.w + s.w);
    }
    ((float4*)resid)[base4 + tid] = v;
  }
  red[tid] = act ? (v.x + v.y + v.z + v.w) : 0.f;
  __syncthreads();
  for (int off = 128; off > 0; off >>= 1) {
    if (tid < off) red[tid] += red[tid + off];
    __syncthreads();
  }
  if (tid == 0) s_mu = red[0] / D_MODEL;
  __syncthreads();
  float mu = s_mu;
  float q = 0.f;
  if (act) {
    float dx = v.x - mu, dy = v.y - mu, dz = v.z - mu, dw = v.w - mu;
    q = dx * dx + dy * dy + dz * dz + dw * dw;
  }
  __syncthreads();
  red[tid] = q; __syncthreads();
  for (int off = 128; off > 0; off >>= 1) {
    if (tid < off) red[tid] += red[tid + off];
    __syncthreads();
  }
  if (tid == 0) s_rs = rsqrtf(red[0] / D_MODEL + 1e-5f);
  __syncthreads();
  float rs = s_rs;
  if (act) {
    float4 wv = ((const float4*)w)[tid];
    float4 bv = ((const float4*)b)[tid];
    float o0 = (v.x - mu) * rs * wv.x + bv.x;
    float o1 = (v.y - mu) * rs * wv.y + bv.y;
    float o2 = (v.z - mu) * rs * wv.z + bv.z;
    float o3 = (v.w - mu) * rs * wv.w + bv.w;
    short4 h, g;
    split_bf16(o0, h.x, g.x); split_bf16(o1, h.y, g.y);
    split_bf16(o2, h.z, g.z); split_bf16(o3, h.w, g.w);
    ((short4*)hh_hi)[base4 + tid] = h;
    ((short4*)hh_lo)[base4 + tid] = g;
  }
}

// ---------------------------------------------------------------------------
// bf16x3 MFMA GEMM:  C[M][N] = A[M][K] . B[N][K]^T  (fp32-equivalent accuracy)
// 128x128 tile, BK=32, 4 waves, global_load_lds staging, source-side XOR
// swizzle mirrored on LDS reads (both-sides rule).
// Split-K: blockIdx.z selects a K-slice; slice z writes partials to C+z*M*N.
// ---------------------------------------------------------------------------
__global__ __launch_bounds__(256) void gemm_bf16x3(
    const short* __restrict__ Ahi, const short* __restrict__ Alo, int lda,
    const short* __restrict__ Bhi, const short* __restrict__ Blo, int ldb,
    float* __restrict__ C, int M, int N, int K) {
  const int BK = 32;
  __shared__ short Ash[128][32];
  __shared__ short Asl[128][32];
  __shared__ short Bsh[128][32];
  __shared__ short Bsl[128][32];
  int brow = blockIdx.y * 128;
  int bcol = blockIdx.x * 128;
  int ksl = K / gridDim.z;
  int kbeg = blockIdx.z * ksl;
  int kend = kbeg + ksl;
  float* Cw = C + (size_t)blockIdx.z * M * N;
  int tid = threadIdx.x;
  int wv = tid >> 6, l = tid & 63;
  int wr = (wv >> 1) * 64;           // wave row origin in tile
  int wc = (wv & 1) * 64;            // wave col origin in tile
  int lrow = l & 15;
  int rslot = ((l >> 4) ^ ((l >> 1) & 3)) * 8;  // swizzled read slot (shorts)
  int lr = l >> 2;                   // staging: row-within-16 group
  int lp = l & 3;                    // staging: physical 16B slot
  float4v zero = {0.f, 0.f, 0.f, 0.f};
  float4v acc[4][4];
#pragma unroll
  for (int m = 0; m < 4; ++m)
#pragma unroll
    for (int n = 0; n < 4; ++n) acc[m][n] = zero;

  for (int k0 = kbeg; k0 < kend; k0 += BK) {
#pragma unroll
    for (int half = 0; half < 2; ++half) {
      int row = wv * 32 + half * 16 + lr;          // per-lane source row
      int s = lp ^ ((row >> 1) & 3);               // pre-swizzled k-slot
      int ldsrow = wv * 32 + half * 16;            // wave-uniform LDS base row
      size_t ao = (size_t)(brow + row) * lda + k0 + s * 8;
      size_t bo = (size_t)(bcol + row) * ldb + k0 + s * 8;
      gload16(Ahi + ao, &Ash[ldsrow][0]);
      gload16(Alo + ao, &Asl[ldsrow][0]);
      gload16(Bhi + bo, &Bsh[ldsrow][0]);
      gload16(Blo + bo, &Bsl[ldsrow][0]);
    }
    __syncthreads();
    short8v ah[4], al[4];
#pragma unroll
    for (int m = 0; m < 4; ++m) {
      int R = wr + m * 16 + lrow;
      ah[m] = *(const short8v*)&Ash[R][rslot];
      al[m] = *(const short8v*)&Asl[R][rslot];
    }
#pragma unroll
    for (int n = 0; n < 4; ++n) {
      int R = wc + n * 16 + lrow;
      short8v bh = *(const short8v*)&Bsh[R][rslot];
      short8v bl = *(const short8v*)&Bsl[R][rslot];
#pragma unroll
      for (int m = 0; m < 4; ++m) {
        acc[m][n] = __builtin_amdgcn_mfma_f32_16x16x32_bf16(ah[m], bh, acc[m][n], 0, 0, 0);
        acc[m][n] = __builtin_amdgcn_mfma_f32_16x16x32_bf16(ah[m], bl, acc[m][n], 0, 0, 0);
        acc[m][n] = __builtin_amdgcn_mfma_f32_16x16x32_bf16(al[m], bh, acc[m][n], 0, 0, 0);
      }
    }
    __syncthreads();
  }
  int drow = (l >> 4) * 4, dcol = l & 15;
#pragma unroll
  for (int m = 0; m < 4; ++m)
#pragma unroll
    for (int n = 0; n < 4; ++n)
#pragma unroll
      for (int j = 0; j < 4; ++j)
        Cw[(size_t)(brow + wr + m * 16 + drow + j) * N + bcol + wc + n * 16 + dcol] =
            acc[m][n][j];
}

// ---------------------------------------------------------------------------
// part[slice][M=4096][80] = u[.,kslice] . xp[.,kslice]^T  (split-K, no atomics)
// ---------------------------------------------------------------------------
__global__ __launch_bounds__(256) void xproj_gemm(
    const float* __restrict__ u, const float* __restrict__ xp,
    float* __restrict__ part) {
  const int BM = 64, BK = 32;
  __shared__ __align__(16) float As[BK][BM + 4];   // stride 68 (16B-aligned)
  __shared__ float Bs[BK][DBC_W + 1];              // stride 81
  int brow = blockIdx.x * BM;
  int kbase = blockIdx.y * XP_KSL;
  int tid = threadIdx.x;
  int tr = (tid / 16) * 4;    // 0..60
  int tc = (tid % 16) * 5;    // 0..75
  float acc[4][5] = {};
  for (int k0 = kbase; k0 < kbase + XP_KSL; k0 += BK) {
#pragma unroll
    for (int it = 0; it < 2; ++it) {           // A: 64 rows x 32 k
      int lin = tid + it * 256;                // 0..511
      int r  = lin >> 3;                       // 0..63
      int kq = (lin & 7) * 4;
      float4 a = *(const float4*)&u[(size_t)(brow + r) * D_INNER + k0 + kq];
      As[kq + 0][r] = a.x; As[kq + 1][r] = a.y;
      As[kq + 2][r] = a.z; As[kq + 3][r] = a.w;
    }
#pragma unroll
    for (int it = 0; it < 3; ++it) {           // B: 80 rows x 32 k
      int lin = tid + it * 256;                // 0..767 (need < 640)
      if (lin < 640) {
        int e  = lin >> 3;                     // 0..79
        int kq = (lin & 7) * 4;
        float4 bv = *(const float4*)&xp[(size_t)e * D_INNER + k0 + kq];
        Bs[kq + 0][e] = bv.x; Bs[kq + 1][e] = bv.y;
        Bs[kq + 2][e] = bv.z; Bs[kq + 3][e] = bv.w;
      }
    }
    __syncthreads();
#pragma unroll
    for (int kk = 0; kk < BK; ++kk) {
      float4 av = *(const float4*)&As[kk][tr];
      float ar[4] = {av.x, av.y, av.z, av.w};
      float br[5];
#pragma unroll
      for (int j = 0; j < 5; ++j) br[j] = Bs[kk][tc + j];
#pragma unroll
      for (int i = 0; i < 4; ++i)
#pragma unroll
        for (int j = 0; j < 5; ++j) acc[i][j] += ar[i] * br[j];
    }
    __syncthreads();
  }
  float* dst = part + (size_t)blockIdx.y * NTOK * DBC_W;
#pragma unroll
  for (int i = 0; i < 4; ++i)
#pragma unroll
    for (int j = 0; j < 5; ++j)
      dst[(size_t)(brow + tr + i) * DBC_W + tc + j] = acc[i][j];
}

// ---------------------------------------------------------------------------
// dbc = sum over XP_KS slices of part.  float4-vectorized.
// ---------------------------------------------------------------------------
__global__ __launch_bounds__(256) void reduce_dbc_kernel(
    const float* __restrict__ part, float* __restrict__ dbc, int n4) {
  int i = blockIdx.x * 256 + threadIdx.x;
  if (i >= n4) return;
  float4 s = ((const float4*)part)[i];
#pragma unroll
  for (int k = 1; k < XP_KS; ++k) {
    float4 v = ((const float4*)(part + (size_t)k * NTOK * DBC_W))[i];
    s.x += v.x; s.y += v.y; s.z += v.z; s.w += v.w;
  }
  ((float4*)dbc)[i] = s;
}

// ---------------------------------------------------------------------------
// Causal depthwise conv (width 4) + bias + SiLU, rolling-window form,
// float4-vectorized over channel groups of 4 (16B loads/stores).
// ---------------------------------------------------------------------------
__global__ __launch_bounds__(256) void conv_silu_kernel(
    const float* __restrict__ xz, const float* __restrict__ cw,
    const float* __restrict__ cb, float* __restrict__ u) {
  int idx = blockIdx.x * 256 + threadIdx.x;
  const int NTC = SEQLEN / CONV_TCH;
  const int C4 = D_INNER / 4;
  if (idx >= BATCH * NTC * C4) return;
  int c4 = idx % C4;
  int tc = (idx / C4) % NTC;
  int b  = idx / (C4 * NTC);
  int t0 = tc * CONV_TCH;
  int c = c4 * 4;
  float4 w0 = ((const float4*)cw)[c + 0];   // cw[c][0..3]
  float4 w1 = ((const float4*)cw)[c + 1];
  float4 w2 = ((const float4*)cw)[c + 2];
  float4 w3 = ((const float4*)cw)[c + 3];
  float4 bias = ((const float4*)cb)[c4];
  const float4* base = (const float4*)(xz + (size_t)b * SEQLEN * (2 * D_INNER)) + c4;
  const int STR = 2 * D_INNER / 4;          // float4 stride per timestep
  float4 xm3 = make_float4(0.f, 0.f, 0.f, 0.f);
  float4 xm2 = xm3, xm1 = xm3;
  if (t0 > 0) {
    xm3 = base[(size_t)(t0 - 3) * STR];
    xm2 = base[(size_t)(t0 - 2) * STR];
    xm1 = base[(size_t)(t0 - 1) * STR];
  }
  float4* ub = (float4*)(u + (size_t)(b * SEQLEN + t0) * D_INNER) + c4;
  const int USTR = D_INNER / 4;
#pragma unroll
  for (int i = 0; i < CONV_TCH; ++i) {
    float4 xt = base[(size_t)(t0 + i) * STR];
    float4 a;
    a.x = bias.x + xm3.x * w0.x + xm2.x * w0.y + xm1.x * w0.z + xt.x * w0.w;
    a.y = bias.y + xm3.y * w1.x + xm2.y * w1.y + xm1.y * w1.z + xt.y * w1.w;
    a.z = bias.z + xm3.z * w2.x + xm2.z * w2.y + xm1.z * w2.z + xt.z * w2.w;
    a.w = bias.w + xm3.w * w3.x + xm2.w * w3.y + xm1.w * w3.z + xt.w * w3.w;
    float4 o;
    o.x = a.x / (1.f + __expf(-a.x));
    o.y = a.y / (1.f + __expf(-a.y));
    o.z = a.z / (1.f + __expf(-a.z));
    o.w = a.w / (1.f + __expf(-a.w));
    ub[(size_t)i * USTR] = o;
    xm3 = xm2; xm2 = xm1; xm1 = xt;
  }
}

__device__ __forceinline__ float softplusf(float a) {
  return (a > 20.f) ? a : log1pf(__expf(a));
}

// ---------------------------------------------------------------------------
// Blocked selective scan, phase 1, dt-projection fused (w in VGPRs).
// No dty store -- scan_chunk2 recomputes the identical dtv.
// ---------------------------------------------------------------------------
__global__ __launch_bounds__(256) void scan_chunk1(
    const float* __restrict__ u,
    const float* __restrict__ dbc, const float* __restrict__ A_log,
    const float* __restrict__ dtw, const float* __restrict__ dtb,
    float* __restrict__ S, float* __restrict__ dtsum) {
  int blk = blockIdx.x;                      // 0 .. BATCH*NC*D_INNER/256-1
  int bcq = (blk * 256) / D_INNER;           // uniform: b*NC + c
  int d = blk * 256 - bcq * D_INNER + threadIdx.x;
  int c = bcq & (NC - 1);
  int b = bcq / NC;
  float A[D_STATE];
#pragma unroll
  for (int s = 0; s < D_STATE; ++s) A[s] = -__expf(A_log[d * D_STATE + s]);
  float w[DT_RANK];
  {
    const float4* w4 = (const float4*)(dtw + (size_t)d * DT_RANK);
#pragma unroll
    for (int j = 0; j < DT_RANK / 4; ++j) {
      float4 v = w4[j];
      w[j * 4 + 0] = v.x; w[j * 4 + 1] = v.y;
      w[j * 4 + 2] = v.z; w[j * 4 + 3] = v.w;
    }
  }
  float bias = dtb[d];
  float h[D_STATE];
#pragma unroll
  for (int s = 0; s < D_STATE; ++s) h[s] = 0.f;
  float dts = 0.f;
  int t0 = c * CHUNK_T;
  for (int t = t0; t < t0 + CHUNK_T; ++t) {
    size_t rowb = (size_t)b * SEQLEN + t;    // uniform
    const float* bc = dbc + rowb * DBC_W;    // uniform address -> s_load
    float raw = bias;
#pragma unroll
    for (int k = 0; k < DT_RANK; ++k) raw += bc[k] * w[k];
    float dtv = softplusf(raw);
    float uv  = u[rowb * D_INNER + d];
    float dtu = dtv * uv;
    dts += dtv;
#pragma unroll
    for (int s = 0; s < D_STATE; ++s) {
      float da = __expf(dtv * A[s]);
      h[s] = da * h[s] + dtu * bc[DT_RANK + s];
    }
  }
  size_t base = (((size_t)b * NC + c) * D_STATE) * D_INNER + d;
#pragma unroll
  for (int s = 0; s < D_STATE; ++s) S[base + (size_t)s * D_INNER] = h[s];
  dtsum[((size_t)b * NC + c) * D_INNER + d] = dts;
}

// ---------------------------------------------------------------------------
// Blocked selective scan, phase 2 (serial chunk combine).
// One thread per (b, s, d).
// ---------------------------------------------------------------------------
__global__ __launch_bounds__(256) void scan_combine(
    float* __restrict__ S, const float* __restrict__ dtsum,
    const float* __restrict__ A_log) {
  int g = blockIdx.x * 256 + threadIdx.x;
  if (g >= BATCH * D_STATE * D_INNER) return;
  int d = g % D_INNER;
  int s = (g / D_INNER) % D_STATE;
  int b = g / (D_INNER * D_STATE);
  float A = -__expf(A_log[d * D_STATE + s]);
  float h = 0.f;
  for (int c = 0; c < NC; ++c) {
    size_t off = (((size_t)b * NC + c) * D_STATE + s) * D_INNER + d;
    float dts = dtsum[((size_t)b * NC + c) * D_INNER + d];
    float Sv = S[off];
    S[off] = h;                          // h_in for chunk c
    h = __expf(dts * A) * h + Sv;
  }
}

// ---------------------------------------------------------------------------
// Blocked selective scan, phase 3.  Recomputes dtv (identical expression to
// scan_chunk1: same inputs -> bitwise identical), applies gating, writes y.
// ---------------------------------------------------------------------------
__global__ __launch_bounds__(256) void scan_chunk2(
    const float* __restrict__ u,
    const float* __restrict__ dbc, const float* __restrict__ xz,
    const float* __restrict__ A_log,
    const float* __restrict__ dtw, const float* __restrict__ dtb,
    const float* __restrict__ Dv, const float* __restrict__ hin,
    short* __restrict__ y_hi, short* __restrict__ y_lo) {
  int blk = blockIdx.x;
  int bcq = (blk * 256) / D_INNER;           // uniform: b*NC + c
  int d = blk * 256 - bcq * D_INNER + threadIdx.x;
  int c = bcq & (NC - 1);
  int b = bcq / NC;
  float A[D_STATE];
#pragma unroll
  for (int s = 0; s < D_STATE; ++s) A[s] = -__expf(A_log[d * D_STATE + s]);
  float w[DT_RANK];
  {
    const float4* w4 = (const float4*)(dtw + (size_t)d * DT_RANK);
#pragma unroll
    for (int j = 0; j < DT_RANK / 4; ++j) {
      float4 v = w4[j];
      w[j * 4 + 0] = v.x; w[j * 4 + 1] = v.y;
      w[j * 4 + 2] = v.z; w[j * 4 + 3] = v.w;
    }
  }
  float bias = dtb[d];
  float Dval = Dv[d];
  float h[D_STATE];
  size_t hbase = (((size_t)b * NC + c) * D_STATE) * D_INNER + d;
#pragma unroll
  for (int s = 0; s < D_STATE; ++s) h[s] = hin[hbase + (size_t)s * D_INNER];
  int t0 = c * CHUNK_T;
  for (int t = t0; t < t0 + CHUNK_T; ++t) {
    size_t rowb = (size_t)b * SEQLEN + t;    // uniform
    const float* bc = dbc + rowb * DBC_W;    // uniform address -> s_load
    float raw = bias;
#pragma unroll
    for (int k = 0; k < DT_RANK; ++k) raw += bc[k] * w[k];
    float dtv = softplusf(raw);
    float uv  = u[rowb * D_INNER + d];
    float dtu = dtv * uv;
    float yv = 0.f;
#pragma unroll
    for (int s = 0; s < D_STATE; ++s) {
      float da = __expf(dtv * A[s]);
      h[s] = da * h[s] + dtu * bc[DT_RANK + s];
      yv += h[s] * bc[DT_RANK + D_STATE + s];
    }
    float zv = xz[rowb * (2 * D_INNER) + D_INNER + d];
    float sig = 1.f / (1.f + __expf(-zv));
    float yo = (yv + uv * Dval) * (zv * sig);
    short hv, lv; split_bf16(yo, hv, lv);
    y_hi[rowb * D_INNER + d] = hv;
    y_lo[rowb * D_INNER + d] = lv;
  }
}

// ---------------------------------------------------------------------------
// Final: out_proj partial-sum + residual add + LN(normf) + LN(dec),
// last rtn tokens only.  float4-vectorized (192 active lanes).
// ---------------------------------------------------------------------------
__global__ __launch_bounds__(256) void final_kernel(
    const float* __restrict__ opart, const float* __restrict__ resid,
    const float* __restrict__ fw, const float* __restrict__ fb,
    const float* __restrict__ dw, const float* __restrict__ db,
    float* __restrict__ out, int rtn) {
  int rowo = blockIdx.x;                 // 0 .. BATCH*rtn-1
  int b = rowo / rtn;
  int t = SEQLEN - rtn + (rowo % rtn);
  int tid = threadIdx.x;
  size_t base4 = ((size_t)b * SEQLEN + t) * (D_MODEL / 4);
  __shared__ float red[256];
  __shared__ float s_mu1, s_rs1, s_mu2, s_rs2;
  bool act = tid < D_MODEL / 4;
  float4 v = make_float4(0.f, 0.f, 0.f, 0.f);
  if (act) {
    float4 o = ((const float4*)opart)[base4 + tid];
    float4 s = make_float4(o.x, o.y, o.z, o.w);
#pragma unroll
    for (int k = 1; k < OP_KS; ++k) {
      float4 o2 = ((const float4*)opart)[(size_t)k * (NTOK * D_MODEL / 4) + base4 + tid];
      s.x += o2.x; s.y += o2.y; s.z += o2.z; s.w += o2.w;
    }
    float4 r = ((const float4*)resid)[base4 + tid];
    v = make_float4(r.x + s.x, r.y + s.y, r.z + s.z, r.w + s.w);
  }
  // --- LN 1 ---
  red[tid] = act ? (v.x + v.y + v.z + v.w) : 0.f;
  __syncthreads();
  for (int off = 128; off > 0; off >>= 1) {
    if (tid < off) red[tid] += red[tid + off];
    __syncthreads();
  }
  if (tid == 0) s_mu1 = red[0] / D_MODEL;
  __syncthreads();
  float mu = s_mu1, q = 0.f;
  if (act) {
    float dx = v.x - mu, dy = v.y - mu, dz = v.z - mu, dww = v.w - mu;
    q = dx * dx + dy * dy + dz * dz + dww * dww;
  }
  __syncthreads();
  red[tid] = q; __syncthreads();
  for (int off = 128; off > 0; off >>= 1) {
    if (tid < off) red[tid] += red[tid + off];
    __syncthreads();
  }
  if (tid == 0) s_rs1 = rsqrtf(red[0] / D_MODEL + 1e-5f);
  __syncthreads();
  float rs = s_rs1;
  if (act) {
    float4 wv = ((const float4*)fw)[tid];
    float4 bv = ((const float4*)fb)[tid];
    v.x = (v.x - mu) * rs * wv.x + bv.x;
    v.y = (v.y - mu) * rs * wv.y + bv.y;
    v.z = (v.z - mu) * rs * wv.z + bv.z;
    v.w = (v.w - mu) * rs * wv.w + bv.w;
  }
  // --- LN 2 ---
  __syncthreads();
  red[tid] = act ? (v.x + v.y + v.z + v.w) : 0.f;
  __syncthreads();
  for (int off = 128; off > 0; off >>= 1) {
    if (tid < off) red[tid] += red[tid + off];
    __syncthreads();
  }
  if (tid == 0) s_mu2 = red[0] / D_MODEL;
  __syncthreads();
  mu = s_mu2; q = 0.f;
  if (act) {
    float dx = v.x - mu, dy = v.y - mu, dz = v.z - mu, dww = v.w - mu;
    q = dx * dx + dy * dy + dz * dz + dww * dww;
  }
  __syncthreads();
  red[tid] = q; __syncthreads();
  for (int off = 128; off > 0; off >>= 1) {
    if (tid < off) red[tid] += red[tid + off];
    __syncthreads();
  }
  if (tid == 0) s_rs2 = rsqrtf(red[0] / D_MODEL + 1e-5f);
  __syncthreads();
  rs = s_rs2;
  if (act) {
    float4 wv = ((const float4*)dw)[tid];
    float4 bv = ((const float4*)db)[tid];
    float4 o;
    o.x = (v.x - mu) * rs * wv.x + bv.x;
    o.y = (v.y - mu) * rs * wv.y + bv.y;
    o.z = (v.z - mu) * rs * wv.z + bv.z;
    o.w = (v.w - mu) * rs * wv.w + bv.w;
    ((float4*)out)[(size_t)rowo * (D_MODEL / 4) + tid] = o;
  }
}

// ---------------------------------------------------------------------------
extern "C" void kernel_launch(void* const* d_in, const int* in_sizes, int n_in,
                              void* d_out, int out_size, void* d_ws, size_t ws_size,
                              hipStream_t stream) {
  const float* x       = (const float*)d_in[0];
  const float* pos     = (const float*)d_in[1];
  const float* norm_w  = (const float*)d_in[2];
  const float* norm_b  = (const float*)d_in[3];
  const float* in_proj = (const float*)d_in[4];
  const float* conv_w  = (const float*)d_in[5];
  const float* conv_b  = (const float*)d_in[6];
  const float* x_proj  = (const float*)d_in[7];
  const float* dt_w    = (const float*)d_in[8];
  const float* dt_b    = (const float*)d_in[9];
  const float* A_log   = (const float*)d_in[10];
  const float* Dv      = (const float*)d_in[11];
  const float* out_proj= (const float*)d_in[12];
  const float* normf_w = (const float*)d_in[13];
  const float* normf_b = (const float*)d_in[14];
  const float* dec_w   = (const float*)d_in[15];
  const float* dec_b   = (const float*)d_in[16];
  int rtn = out_size / (BATCH * D_MODEL);   // return_token_num

  const size_t WI = (size_t)2 * D_INNER * D_MODEL;   // in_proj elems / layer
  const size_t WO = (size_t)D_MODEL * D_INNER;       // out_proj elems / layer

  float* ws    = (float*)d_ws;
  float* resid = ws;                                 // NTOK*D_MODEL
  float* xz    = resid + (size_t)NTOK * D_MODEL;     // NTOK*2*D_INNER (also opart)
  float* u     = xz    + (size_t)NTOK * 2 * D_INNER; // NTOK*D_INNER
  float* dbc   = u     + (size_t)NTOK * D_INNER;     // NTOK*80
  float* Sbuf  = dbc   + (size_t)NTOK * DBC_W;       // BATCH*NC*D_STATE*D_INNER
  float* dtsum = Sbuf  + (size_t)BATCH * NC * D_STATE * D_INNER; // BATCH*NC*D_INNER
  // dbcp (XP_KS*NTOK*80 = 21.0 MB) aliases Sbuf (25.2 MB): xproj+reduce_dbc
  // finish before scan_chunk1 writes S.
  float* dbcp  = Sbuf;
  short* hh_hi = (short*)(dtsum + (size_t)BATCH * NC * D_INNER);
  short* hh_lo = hh_hi + (size_t)NTOK * D_MODEL;
  short* y_hi  = hh_lo + (size_t)NTOK * D_MODEL;
  short* y_lo  = y_hi  + (size_t)NTOK * D_INNER;
  short* wIh   = y_lo  + (size_t)NTOK * D_INNER;     // 8 layers in_proj hi
  short* wIl   = wIh + N_LAYER * WI;                 // 8 layers in_proj lo
  short* wOh   = wIl + N_LAYER * WI;                 // 8 layers out_proj hi
  short* wOl   = wOh + N_LAYER * WO;                 // 8 layers out_proj lo
  float* opart = xz;   // out_proj split-K partials reuse xz (z dead by then)

  // Hoisted weight splits: all layers at once (weights are layer-constant).
  split_kernel<<<2048, 256, 0, stream>>>(in_proj, wIh, wIl,
                                         (int)(N_LAYER * WI / 4));
  split_kernel<<<2048, 256, 0, stream>>>(out_proj, wOh, wOl,
                                         (int)(N_LAYER * WO / 4));

  for (int l = 0; l < N_LAYER; ++l) {
    ln_kernel<<<NTOK, 256, 0, stream>>>(x, pos, resid, opart, hh_hi, hh_lo,
        norm_w + l * D_MODEL, norm_b + l * D_MODEL, l == 0);

    dim3 g1(2 * D_INNER / 128, NTOK / 128, 1);
    gemm_bf16x3<<<g1, 256, 0, stream>>>(hh_hi, hh_lo, D_MODEL,
        wIh + l * WI, wIl + l * WI, D_MODEL, xz, NTOK, 2 * D_INNER, D_MODEL);

    int convtot = BATCH * (SEQLEN / CONV_TCH) * (D_INNER / 4);
    conv_silu_kernel<<<(convtot + 255) / 256, 256, 0, stream>>>(
        xz, conv_w + (size_t)l * D_INNER * D_CONV, conv_b + l * D_INNER, u);

    dim3 gxp(NTOK / 64, XP_KS);
    xproj_gemm<<<gxp, 256, 0, stream>>>(
        u, x_proj + (size_t)l * DBC_W * D_INNER, dbcp);
    reduce_dbc_kernel<<<(NTOK * DBC_W / 4 + 255) / 256, 256, 0, stream>>>(
        dbcp, dbc, NTOK * DBC_W / 4);

    const float* Al = A_log + (size_t)l * D_INNER * D_STATE;
    const float* dtwl = dt_w + (size_t)l * D_INNER * DT_RANK;
    const float* dtbl = dt_b + (size_t)l * D_INNER;
    int tot1 = BATCH * NC * D_INNER;
    scan_chunk1<<<tot1 / 256, 256, 0, stream>>>(
        u, dbc, Al, dtwl, dtbl, Sbuf, dtsum);
    scan_combine<<<(BATCH * D_STATE * D_INNER + 255) / 256, 256, 0, stream>>>(
        Sbuf, dtsum, Al);
    scan_chunk2<<<tot1 / 256, 256, 0, stream>>>(
        u, dbc, xz, Al, dtwl, dtbl, Dv + l * D_INNER, Sbuf, y_hi, y_lo);

    // out_proj split-K=4: partials into opart (reused xz); reduction fused
    // into next layer's ln_kernel / final_kernel.
    dim3 g2(D_MODEL / 128, NTOK / 128, OP_KS);
    gemm_bf16x3<<<g2, 256, 0, stream>>>(y_hi, y_lo, D_INNER,
        wOh + l * WO, wOl + l * WO, D_INNER, opart, NTOK, D_MODEL, D_INNER);
  }

  final_kernel<<<BATCH * rtn, 256, 0, stream>>>(
      opart, resid, normf_w, normf_b, dec_w, dec_b, (float*)d_out, rtn);
}

// Round 14
// 2134.739 us; speedup vs baseline: 1.1291x; 1.1291x over previous
//
#include <hip/hip_runtime.h>
#include <math.h>

#define D_MODEL 768
#define N_LAYER 8
#define D_INNER 1536
#define D_STATE 16
#define DT_RANK 48
#define D_CONV  4
#define BATCH   4
#define SEQLEN  1024
#define NTOK    (BATCH*SEQLEN)      // 4096 token rows
#define DBC_W   (DT_RANK + 2*D_STATE)  // 80
#define NC      64                  // scan chunks per sequence
#define CHUNK_T (SEQLEN/NC)         // 16 timesteps per chunk
#define XP_KS   16                  // xproj split-K slices
#define XP_KSL  (D_INNER/XP_KS)     // 96 k per slice
#define CONV_TCH 16                 // conv outputs per thread
#define OP_KS   4                   // out_proj split-K slices

typedef __attribute__((ext_vector_type(8))) short short8v;   // 8 bf16 (4 VGPRs)
typedef __attribute__((ext_vector_type(4))) float float4v;   // 4 fp32 acc

// Split fp32 into hi+lo bf16 (both RNE).  x ~= hi + lo, |err| ~ 2^-17 |x|.
__device__ __forceinline__ void split_bf16(float x, short& hi, short& lo) {
  unsigned u = __float_as_uint(x);
  unsigned r = (u + 0x7fffu + ((u >> 16) & 1u)) >> 16;
  hi = (short)r;
  float fhi = __uint_as_float(r << 16);
  float xl = x - fhi;
  unsigned u2 = __float_as_uint(xl);
  unsigned r2 = (u2 + 0x7fffu + ((u2 >> 16) & 1u)) >> 16;
  lo = (short)r2;
}

// Async global->LDS 16B copy: per-lane global src, wave-uniform LDS base;
// lane i's 16B lands at ldsbase + i*16.
__device__ __forceinline__ void gload16(const short* g, short* l) {
  __builtin_amdgcn_global_load_lds(
      (const __attribute__((address_space(1))) void*)g,
      (__attribute__((address_space(3))) void*)l, 16, 0, 0);
}

// ---------------------------------------------------------------------------
// Weight split: fp32 [n] -> bf16 hi[n], lo[n].  n4 = n/4, float4-vectorized.
// Called ONCE per launch for all layers' weights (hoisted out of layer loop).
// ---------------------------------------------------------------------------
__global__ __launch_bounds__(256) void split_kernel(
    const float* __restrict__ src, short* __restrict__ hi,
    short* __restrict__ lo, int n4) {
  int stride = gridDim.x * 256;
  for (int i = blockIdx.x * 256 + threadIdx.x; i < n4; i += stride) {
    float4 v = ((const float4*)src)[i];
    short4 h, g;
    split_bf16(v.x, h.x, g.x);
    split_bf16(v.y, h.y, g.y);
    split_bf16(v.z, h.z, g.z);
    split_bf16(v.w, h.w, g.w);
    ((short4*)hi)[i] = h;
    ((short4*)lo)[i] = g;
  }
}

// ---------------------------------------------------------------------------
// LayerNorm + residual update, with out_proj split-K reduction FUSED.
// float4-vectorized: threads 0..191 each own one float4 of the 768-row.
// first=1: r = x + pos.  first=0: r = resid + sum_k opart[k].
// ---------------------------------------------------------------------------
__global__ __launch_bounds__(256) void ln_kernel(
    const float* __restrict__ x, const float* __restrict__ pos,
    float* __restrict__ resid, const float* __restrict__ opart,
    short* __restrict__ hh_hi, short* __restrict__ hh_lo,
    const float* __restrict__ w, const float* __restrict__ b, int first) {
  int row = blockIdx.x;
  int tid = threadIdx.x;
  size_t base4 = (size_t)row * (D_MODEL / 4);   // float4 index of row start
  __shared__ float red[256];
  __shared__ float s_mu, s_rs;
  float4 v = make_float4(0.f, 0.f, 0.f, 0.f);
  bool act = tid < D_MODEL / 4;                 // 192 active lanes
  if (act) {
    if (first) {
      float4 a = ((const float4*)x)[base4 + tid];
      float4 p = ((const float4*)pos)[base4 + tid];
      v = make_float4(a.x + p.x, a.y + p.y, a.z + p.z, a.w + p.w);
    } else {
      float4 r = ((const float4*)resid)[base4 + tid];
      float4 o = ((const float4*)opart)[base4 + tid];
      float4 s = make_float4(o.x, o.y, o.z, o.w);
#pragma unroll
      for (int k = 1; k < OP_KS; ++k) {
        float4 o2 = ((const float4*)opart)[(size_t)k * (NTOK * D_MODEL / 4) + base4 + tid];
        s.x += o2.x; s.y += o2.y; s.z += o2.z; s.w += o2.w;
      }
      v = make_float4(r.x + s.x, r.y + s.y, r.z + s.z, r.w + s.w);
    }
    ((float4*)resid)[base4 + tid] = v;
  }
  red[tid] = act ? (v.x + v.y + v.z + v.w) : 0.f;
  __syncthreads();
  for (int off = 128; off > 0; off >>= 1) {
    if (tid < off) red[tid] += red[tid + off];
    __syncthreads();
  }
  if (tid == 0) s_mu = red[0] / D_MODEL;
  __syncthreads();
  float mu = s_mu;
  float q = 0.f;
  if (act) {
    float dx = v.x - mu, dy = v.y - mu, dz = v.z - mu, dw = v.w - mu;
    q = dx * dx + dy * dy + dz * dz + dw * dw;
  }
  __syncthreads();
  red[tid] = q; __syncthreads();
  for (int off = 128; off > 0; off >>= 1) {
    if (tid < off) red[tid] += red[tid + off];
    __syncthreads();
  }
  if (tid == 0) s_rs = rsqrtf(red[0] / D_MODEL + 1e-5f);
  __syncthreads();
  float rs = s_rs;
  if (act) {
    float4 wv = ((const float4*)w)[tid];
    float4 bv = ((const float4*)b)[tid];
    float o0 = (v.x - mu) * rs * wv.x + bv.x;
    float o1 = (v.y - mu) * rs * wv.y + bv.y;
    float o2 = (v.z - mu) * rs * wv.z + bv.z;
    float o3 = (v.w - mu) * rs * wv.w + bv.w;
    short4 h, g;
    split_bf16(o0, h.x, g.x); split_bf16(o1, h.y, g.y);
    split_bf16(o2, h.z, g.z); split_bf16(o3, h.w, g.w);
    ((short4*)hh_hi)[base4 + tid] = h;
    ((short4*)hh_lo)[base4 + tid] = g;
  }
}

// ---------------------------------------------------------------------------
// bf16x3 MFMA GEMM:  C[M][N] = A[M][K] . B[N][K]^T  (fp32-equivalent accuracy)
// 128x128 tile, BK=32, 4 waves, global_load_lds staging, source-side XOR
// swizzle mirrored on LDS reads (both-sides rule).
// Split-K: blockIdx.z selects a K-slice; slice z writes partials to C+z*M*N.
// ---------------------------------------------------------------------------
__global__ __launch_bounds__(256) void gemm_bf16x3(
    const short* __restrict__ Ahi, const short* __restrict__ Alo, int lda,
    const short* __restrict__ Bhi, const short* __restrict__ Blo, int ldb,
    float* __restrict__ C, int M, int N, int K) {
  const int BK = 32;
  __shared__ short Ash[128][32];
  __shared__ short Asl[128][32];
  __shared__ short Bsh[128][32];
  __shared__ short Bsl[128][32];
  int brow = blockIdx.y * 128;
  int bcol = blockIdx.x * 128;
  int ksl = K / gridDim.z;
  int kbeg = blockIdx.z * ksl;
  int kend = kbeg + ksl;
  float* Cw = C + (size_t)blockIdx.z * M * N;
  int tid = threadIdx.x;
  int wv = tid >> 6, l = tid & 63;
  int wr = (wv >> 1) * 64;           // wave row origin in tile
  int wc = (wv & 1) * 64;            // wave col origin in tile
  int lrow = l & 15;
  int rslot = ((l >> 4) ^ ((l >> 1) & 3)) * 8;  // swizzled read slot (shorts)
  int lr = l >> 2;                   // staging: row-within-16 group
  int lp = l & 3;                    // staging: physical 16B slot
  float4v zero = {0.f, 0.f, 0.f, 0.f};
  float4v acc[4][4];
#pragma unroll
  for (int m = 0; m < 4; ++m)
#pragma unroll
    for (int n = 0; n < 4; ++n) acc[m][n] = zero;

  for (int k0 = kbeg; k0 < kend; k0 += BK) {
#pragma unroll
    for (int half = 0; half < 2; ++half) {
      int row = wv * 32 + half * 16 + lr;          // per-lane source row
      int s = lp ^ ((row >> 1) & 3);               // pre-swizzled k-slot
      int ldsrow = wv * 32 + half * 16;            // wave-uniform LDS base row
      size_t ao = (size_t)(brow + row) * lda + k0 + s * 8;
      size_t bo = (size_t)(bcol + row) * ldb + k0 + s * 8;
      gload16(Ahi + ao, &Ash[ldsrow][0]);
      gload16(Alo + ao, &Asl[ldsrow][0]);
      gload16(Bhi + bo, &Bsh[ldsrow][0]);
      gload16(Blo + bo, &Bsl[ldsrow][0]);
    }
    __syncthreads();
    short8v ah[4], al[4];
#pragma unroll
    for (int m = 0; m < 4; ++m) {
      int R = wr + m * 16 + lrow;
      ah[m] = *(const short8v*)&Ash[R][rslot];
      al[m] = *(const short8v*)&Asl[R][rslot];
    }
#pragma unroll
    for (int n = 0; n < 4; ++n) {
      int R = wc + n * 16 + lrow;
      short8v bh = *(const short8v*)&Bsh[R][rslot];
      short8v bl = *(const short8v*)&Bsl[R][rslot];
#pragma unroll
      for (int m = 0; m < 4; ++m) {
        acc[m][n] = __builtin_amdgcn_mfma_f32_16x16x32_bf16(ah[m], bh, acc[m][n], 0, 0, 0);
        acc[m][n] = __builtin_amdgcn_mfma_f32_16x16x32_bf16(ah[m], bl, acc[m][n], 0, 0, 0);
        acc[m][n] = __builtin_amdgcn_mfma_f32_16x16x32_bf16(al[m], bh, acc[m][n], 0, 0, 0);
      }
    }
    __syncthreads();
  }
  int drow = (l >> 4) * 4, dcol = l & 15;
#pragma unroll
  for (int m = 0; m < 4; ++m)
#pragma unroll
    for (int n = 0; n < 4; ++n)
#pragma unroll
      for (int j = 0; j < 4; ++j)
        Cw[(size_t)(brow + wr + m * 16 + drow + j) * N + bcol + wc + n * 16 + dcol] =
            acc[m][n][j];
}

// ---------------------------------------------------------------------------
// part[slice][M=4096][80] = u[.,kslice] . xp[.,kslice]^T  (split-K, no atomics)
// ---------------------------------------------------------------------------
__global__ __launch_bounds__(256) void xproj_gemm(
    const float* __restrict__ u, const float* __restrict__ xp,
    float* __restrict__ part) {
  const int BM = 64, BK = 32;
  __shared__ __align__(16) float As[BK][BM + 4];   // stride 68 (16B-aligned)
  __shared__ float Bs[BK][DBC_W + 1];              // stride 81
  int brow = blockIdx.x * BM;
  int kbase = blockIdx.y * XP_KSL;
  int tid = threadIdx.x;
  int tr = (tid / 16) * 4;    // 0..60
  int tc = (tid % 16) * 5;    // 0..75
  float acc[4][5] = {};
  for (int k0 = kbase; k0 < kbase + XP_KSL; k0 += BK) {
#pragma unroll
    for (int it = 0; it < 2; ++it) {           // A: 64 rows x 32 k
      int lin = tid + it * 256;                // 0..511
      int r  = lin >> 3;                       // 0..63
      int kq = (lin & 7) * 4;
      float4 a = *(const float4*)&u[(size_t)(brow + r) * D_INNER + k0 + kq];
      As[kq + 0][r] = a.x; As[kq + 1][r] = a.y;
      As[kq + 2][r] = a.z; As[kq + 3][r] = a.w;
    }
#pragma unroll
    for (int it = 0; it < 3; ++it) {           // B: 80 rows x 32 k
      int lin = tid + it * 256;                // 0..767 (need < 640)
      if (lin < 640) {
        int e  = lin >> 3;                     // 0..79
        int kq = (lin & 7) * 4;
        float4 bv = *(const float4*)&xp[(size_t)e * D_INNER + k0 + kq];
        Bs[kq + 0][e] = bv.x; Bs[kq + 1][e] = bv.y;
        Bs[kq + 2][e] = bv.z; Bs[kq + 3][e] = bv.w;
      }
    }
    __syncthreads();
#pragma unroll
    for (int kk = 0; kk < BK; ++kk) {
      float4 av = *(const float4*)&As[kk][tr];
      float ar[4] = {av.x, av.y, av.z, av.w};
      float br[5];
#pragma unroll
      for (int j = 0; j < 5; ++j) br[j] = Bs[kk][tc + j];
#pragma unroll
      for (int i = 0; i < 4; ++i)
#pragma unroll
        for (int j = 0; j < 5; ++j) acc[i][j] += ar[i] * br[j];
    }
    __syncthreads();
  }
  float* dst = part + (size_t)blockIdx.y * NTOK * DBC_W;
#pragma unroll
  for (int i = 0; i < 4; ++i)
#pragma unroll
    for (int j = 0; j < 5; ++j)
      dst[(size_t)(brow + tr + i) * DBC_W + tc + j] = acc[i][j];
}

// ---------------------------------------------------------------------------
// dbc = sum over XP_KS slices of part.  float4-vectorized.
// ---------------------------------------------------------------------------
__global__ __launch_bounds__(256) void reduce_dbc_kernel(
    const float* __restrict__ part, float* __restrict__ dbc, int n4) {
  int i = blockIdx.x * 256 + threadIdx.x;
  if (i >= n4) return;
  float4 s = ((const float4*)part)[i];
#pragma unroll
  for (int k = 1; k < XP_KS; ++k) {
    float4 v = ((const float4*)(part + (size_t)k * NTOK * DBC_W))[i];
    s.x += v.x; s.y += v.y; s.z += v.z; s.w += v.w;
  }
  ((float4*)dbc)[i] = s;
}

// ---------------------------------------------------------------------------
// Causal depthwise conv (width 4) + bias + SiLU, rolling-window form,
// float4-vectorized over channel groups of 4 (16B loads/stores).
// ---------------------------------------------------------------------------
__global__ __launch_bounds__(256) void conv_silu_kernel(
    const float* __restrict__ xz, const float* __restrict__ cw,
    const float* __restrict__ cb, float* __restrict__ u) {
  int idx = blockIdx.x * 256 + threadIdx.x;
  const int NTC = SEQLEN / CONV_TCH;
  const int C4 = D_INNER / 4;
  if (idx >= BATCH * NTC * C4) return;
  int c4 = idx % C4;
  int tc = (idx / C4) % NTC;
  int b  = idx / (C4 * NTC);
  int t0 = tc * CONV_TCH;
  int c = c4 * 4;
  float4 w0 = ((const float4*)cw)[c + 0];   // cw[c][0..3]
  float4 w1 = ((const float4*)cw)[c + 1];
  float4 w2 = ((const float4*)cw)[c + 2];
  float4 w3 = ((const float4*)cw)[c + 3];
  float4 bias = ((const float4*)cb)[c4];
  const float4* base = (const float4*)(xz + (size_t)b * SEQLEN * (2 * D_INNER)) + c4;
  const int STR = 2 * D_INNER / 4;          // float4 stride per timestep
  float4 xm3 = make_float4(0.f, 0.f, 0.f, 0.f);
  float4 xm2 = xm3, xm1 = xm3;
  if (t0 > 0) {
    xm3 = base[(size_t)(t0 - 3) * STR];
    xm2 = base[(size_t)(t0 - 2) * STR];
    xm1 = base[(size_t)(t0 - 1) * STR];
  }
  float4* ub = (float4*)(u + (size_t)(b * SEQLEN + t0) * D_INNER) + c4;
  const int USTR = D_INNER / 4;
#pragma unroll
  for (int i = 0; i < CONV_TCH; ++i) {
    float4 xt = base[(size_t)(t0 + i) * STR];
    float4 a;
    a.x = bias.x + xm3.x * w0.x + xm2.x * w0.y + xm1.x * w0.z + xt.x * w0.w;
    a.y = bias.y + xm3.y * w1.x + xm2.y * w1.y + xm1.y * w1.z + xt.y * w1.w;
    a.z = bias.z + xm3.z * w2.x + xm2.z * w2.y + xm1.z * w2.z + xt.z * w2.w;
    a.w = bias.w + xm3.w * w3.x + xm2.w * w3.y + xm1.w * w3.z + xt.w * w3.w;
    float4 o;
    o.x = a.x / (1.f + __expf(-a.x));
    o.y = a.y / (1.f + __expf(-a.y));
    o.z = a.z / (1.f + __expf(-a.z));
    o.w = a.w / (1.f + __expf(-a.w));
    ub[(size_t)i * USTR] = o;
    xm3 = xm2; xm2 = xm1; xm1 = xt;
  }
}

__device__ __forceinline__ float softplusf(float a) {
  return (a > 20.f) ? a : log1pf(__expf(a));
}

// ---------------------------------------------------------------------------
// Blocked selective scan, phase 1, dt-projection fused (w in VGPRs).
// Stores the ACTIVATED dtv to dty (scan_chunk2 reads it -- recomputing the
// 48-FMA dot there made chunk2 VALU-bound, round-13 lesson).
// ---------------------------------------------------------------------------
__global__ __launch_bounds__(256) void scan_chunk1(
    float* __restrict__ dty, const float* __restrict__ u,
    const float* __restrict__ dbc, const float* __restrict__ A_log,
    const float* __restrict__ dtw, const float* __restrict__ dtb,
    float* __restrict__ S, float* __restrict__ dtsum) {
  int blk = blockIdx.x;                      // 0 .. BATCH*NC*D_INNER/256-1
  int bcq = (blk * 256) / D_INNER;           // uniform: b*NC + c
  int d = blk * 256 - bcq * D_INNER + threadIdx.x;
  int c = bcq & (NC - 1);
  int b = bcq / NC;
  float A[D_STATE];
#pragma unroll
  for (int s = 0; s < D_STATE; ++s) A[s] = -__expf(A_log[d * D_STATE + s]);
  float w[DT_RANK];
  {
    const float4* w4 = (const float4*)(dtw + (size_t)d * DT_RANK);
#pragma unroll
    for (int j = 0; j < DT_RANK / 4; ++j) {
      float4 v = w4[j];
      w[j * 4 + 0] = v.x; w[j * 4 + 1] = v.y;
      w[j * 4 + 2] = v.z; w[j * 4 + 3] = v.w;
    }
  }
  float bias = dtb[d];
  float h[D_STATE];
#pragma unroll
  for (int s = 0; s < D_STATE; ++s) h[s] = 0.f;
  float dts = 0.f;
  int t0 = c * CHUNK_T;
  for (int t = t0; t < t0 + CHUNK_T; ++t) {
    size_t rowb = (size_t)b * SEQLEN + t;    // uniform
    const float* bc = dbc + rowb * DBC_W;    // uniform address -> s_load
    float raw = bias;
#pragma unroll
    for (int k = 0; k < DT_RANK; ++k) raw += bc[k] * w[k];
    float dtv = softplusf(raw);
    dty[rowb * D_INNER + d] = dtv;           // for scan_chunk2
    float uv  = u[rowb * D_INNER + d];
    float dtu = dtv * uv;
    dts += dtv;
#pragma unroll
    for (int s = 0; s < D_STATE; ++s) {
      float da = __expf(dtv * A[s]);
      h[s] = da * h[s] + dtu * bc[DT_RANK + s];
    }
  }
  size_t base = (((size_t)b * NC + c) * D_STATE) * D_INNER + d;
#pragma unroll
  for (int s = 0; s < D_STATE; ++s) S[base + (size_t)s * D_INNER] = h[s];
  dtsum[((size_t)b * NC + c) * D_INNER + d] = dts;
}

// ---------------------------------------------------------------------------
// Blocked selective scan, phase 2 (serial chunk combine).
// One thread per (b, s, d).
// ---------------------------------------------------------------------------
__global__ __launch_bounds__(256) void scan_combine(
    float* __restrict__ S, const float* __restrict__ dtsum,
    const float* __restrict__ A_log) {
  int g = blockIdx.x * 256 + threadIdx.x;
  if (g >= BATCH * D_STATE * D_INNER) return;
  int d = g % D_INNER;
  int s = (g / D_INNER) % D_STATE;
  int b = g / (D_INNER * D_STATE);
  float A = -__expf(A_log[d * D_STATE + s]);
  float h = 0.f;
  for (int c = 0; c < NC; ++c) {
    size_t off = (((size_t)b * NC + c) * D_STATE + s) * D_INNER + d;
    float dts = dtsum[((size_t)b * NC + c) * D_INNER + d];
    float Sv = S[off];
    S[off] = h;                          // h_in for chunk c
    h = __expf(dts * A) * h + Sv;
  }
}

// ---------------------------------------------------------------------------
// Blocked selective scan, phase 3.  Reads activated dtv from dty.
// ---------------------------------------------------------------------------
__global__ __launch_bounds__(256) void scan_chunk2(
    const float* __restrict__ dty, const float* __restrict__ u,
    const float* __restrict__ dbc, const float* __restrict__ xz,
    const float* __restrict__ A_log,
    const float* __restrict__ Dv, const float* __restrict__ hin,
    short* __restrict__ y_hi, short* __restrict__ y_lo) {
  int blk = blockIdx.x;
  int bcq = (blk * 256) / D_INNER;           // uniform: b*NC + c
  int d = blk * 256 - bcq * D_INNER + threadIdx.x;
  int c = bcq & (NC - 1);
  int b = bcq / NC;
  float A[D_STATE];
#pragma unroll
  for (int s = 0; s < D_STATE; ++s) A[s] = -__expf(A_log[d * D_STATE + s]);
  float Dval = Dv[d];
  float h[D_STATE];
  size_t hbase = (((size_t)b * NC + c) * D_STATE) * D_INNER + d;
#pragma unroll
  for (int s = 0; s < D_STATE; ++s) h[s] = hin[hbase + (size_t)s * D_INNER];
  int t0 = c * CHUNK_T;
  for (int t = t0; t < t0 + CHUNK_T; ++t) {
    size_t rowb = (size_t)b * SEQLEN + t;    // uniform
    const float* bc = dbc + rowb * DBC_W;    // uniform address -> s_load
    float dtv = dty[rowb * D_INNER + d];     // already softplus'd
    float uv  = u[rowb * D_INNER + d];
    float dtu = dtv * uv;
    float yv = 0.f;
#pragma unroll
    for (int s = 0; s < D_STATE; ++s) {
      float da = __expf(dtv * A[s]);
      h[s] = da * h[s] + dtu * bc[DT_RANK + s];
      yv += h[s] * bc[DT_RANK + D_STATE + s];
    }
    float zv = xz[rowb * (2 * D_INNER) + D_INNER + d];
    float sig = 1.f / (1.f + __expf(-zv));
    float yo = (yv + uv * Dval) * (zv * sig);
    short hv, lv; split_bf16(yo, hv, lv);
    y_hi[rowb * D_INNER + d] = hv;
    y_lo[rowb * D_INNER + d] = lv;
  }
}

// ---------------------------------------------------------------------------
// Final: out_proj partial-sum + residual add + LN(normf) + LN(dec),
// last rtn tokens only.  float4-vectorized (192 active lanes).
// ---------------------------------------------------------------------------
__global__ __launch_bounds__(256) void final_kernel(
    const float* __restrict__ opart, const float* __restrict__ resid,
    const float* __restrict__ fw, const float* __restrict__ fb,
    const float* __restrict__ dw, const float* __restrict__ db,
    float* __restrict__ out, int rtn) {
  int rowo = blockIdx.x;                 // 0 .. BATCH*rtn-1
  int b = rowo / rtn;
  int t = SEQLEN - rtn + (rowo % rtn);
  int tid = threadIdx.x;
  size_t base4 = ((size_t)b * SEQLEN + t) * (D_MODEL / 4);
  __shared__ float red[256];
  __shared__ float s_mu1, s_rs1, s_mu2, s_rs2;
  bool act = tid < D_MODEL / 4;
  float4 v = make_float4(0.f, 0.f, 0.f, 0.f);
  if (act) {
    float4 o = ((const float4*)opart)[base4 + tid];
    float4 s = make_float4(o.x, o.y, o.z, o.w);
#pragma unroll
    for (int k = 1; k < OP_KS; ++k) {
      float4 o2 = ((const float4*)opart)[(size_t)k * (NTOK * D_MODEL / 4) + base4 + tid];
      s.x += o2.x; s.y += o2.y; s.z += o2.z; s.w += o2.w;
    }
    float4 r = ((const float4*)resid)[base4 + tid];
    v = make_float4(r.x + s.x, r.y + s.y, r.z + s.z, r.w + s.w);
  }
  // --- LN 1 ---
  red[tid] = act ? (v.x + v.y + v.z + v.w) : 0.f;
  __syncthreads();
  for (int off = 128; off > 0; off >>= 1) {
    if (tid < off) red[tid] += red[tid + off];
    __syncthreads();
  }
  if (tid == 0) s_mu1 = red[0] / D_MODEL;
  __syncthreads();
  float mu = s_mu1, q = 0.f;
  if (act) {
    float dx = v.x - mu, dy = v.y - mu, dz = v.z - mu, dww = v.w - mu;
    q = dx * dx + dy * dy + dz * dz + dww * dww;
  }
  __syncthreads();
  red[tid] = q; __syncthreads();
  for (int off = 128; off > 0; off >>= 1) {
    if (tid < off) red[tid] += red[tid + off];
    __syncthreads();
  }
  if (tid == 0) s_rs1 = rsqrtf(red[0] / D_MODEL + 1e-5f);
  __syncthreads();
  float rs = s_rs1;
  if (act) {
    float4 wv = ((const float4*)fw)[tid];
    float4 bv = ((const float4*)fb)[tid];
    v.x = (v.x - mu) * rs * wv.x + bv.x;
    v.y = (v.y - mu) * rs * wv.y + bv.y;
    v.z = (v.z - mu) * rs * wv.z + bv.z;
    v.w = (v.w - mu) * rs * wv.w + bv.w;
  }
  // --- LN 2 ---
  __syncthreads();
  red[tid] = act ? (v.x + v.y + v.z + v.w) : 0.f;
  __syncthreads();
  for (int off = 128; off > 0; off >>= 1) {
    if (tid < off) red[tid] += red[tid + off];
    __syncthreads();
  }
  if (tid == 0) s_mu2 = red[0] / D_MODEL;
  __syncthreads();
  mu = s_mu2; q = 0.f;
  if (act) {
    float dx = v.x - mu, dy = v.y - mu, dz = v.z - mu, dww = v.w - mu;
    q = dx * dx + dy * dy + dz * dz + dww * dww;
  }
  __syncthreads();
  red[tid] = q; __syncthreads();
  for (int off = 128; off > 0; off >>= 1) {
    if (tid < off) red[tid] += red[tid + off];
    __syncthreads();
  }
  if (tid == 0) s_rs2 = rsqrtf(red[0] / D_MODEL + 1e-5f);
  __syncthreads();
  rs = s_rs2;
  if (act) {
    float4 wv = ((const float4*)dw)[tid];
    float4 bv = ((const float4*)db)[tid];
    float4 o;
    o.x = (v.x - mu) * rs * wv.x + bv.x;
    o.y = (v.y - mu) * rs * wv.y + bv.y;
    o.z = (v.z - mu) * rs * wv.z + bv.z;
    o.w = (v.w - mu) * rs * wv.w + bv.w;
    ((float4*)out)[(size_t)rowo * (D_MODEL / 4) + tid] = o;
  }
}

// ---------------------------------------------------------------------------
extern "C" void kernel_launch(void* const* d_in, const int* in_sizes, int n_in,
                              void* d_out, int out_size, void* d_ws, size_t ws_size,
                              hipStream_t stream) {
  const float* x       = (const float*)d_in[0];
  const float* pos     = (const float*)d_in[1];
  const float* norm_w  = (const float*)d_in[2];
  const float* norm_b  = (const float*)d_in[3];
  const float* in_proj = (const float*)d_in[4];
  const float* conv_w  = (const float*)d_in[5];
  const float* conv_b  = (const float*)d_in[6];
  const float* x_proj  = (const float*)d_in[7];
  const float* dt_w    = (const float*)d_in[8];
  const float* dt_b    = (const float*)d_in[9];
  const float* A_log   = (const float*)d_in[10];
  const float* Dv      = (const float*)d_in[11];
  const float* out_proj= (const float*)d_in[12];
  const float* normf_w = (const float*)d_in[13];
  const float* normf_b = (const float*)d_in[14];
  const float* dec_w   = (const float*)d_in[15];
  const float* dec_b   = (const float*)d_in[16];
  int rtn = out_size / (BATCH * D_MODEL);   // return_token_num

  const size_t WI = (size_t)2 * D_INNER * D_MODEL;   // in_proj elems / layer
  const size_t WO = (size_t)D_MODEL * D_INNER;       // out_proj elems / layer

  float* ws    = (float*)d_ws;
  float* resid = ws;                                 // NTOK*D_MODEL
  float* xz    = resid + (size_t)NTOK * D_MODEL;     // NTOK*2*D_INNER (also opart)
  float* u     = xz    + (size_t)NTOK * 2 * D_INNER; // NTOK*D_INNER
  float* dbc   = u     + (size_t)NTOK * D_INNER;     // NTOK*80
  float* dty   = dbc   + (size_t)NTOK * DBC_W;       // NTOK*D_INNER (softplus dt)
  float* Sbuf  = dty   + (size_t)NTOK * D_INNER;     // BATCH*NC*D_STATE*D_INNER
  float* dtsum = Sbuf  + (size_t)BATCH * NC * D_STATE * D_INNER; // BATCH*NC*D_INNER
  // dbcp (XP_KS*NTOK*80 = 21.0 MB) aliases Sbuf (25.2 MB): xproj+reduce_dbc
  // finish before scan_chunk1 writes S.
  float* dbcp  = Sbuf;
  short* hh_hi = (short*)(dtsum + (size_t)BATCH * NC * D_INNER);
  short* hh_lo = hh_hi + (size_t)NTOK * D_MODEL;
  short* y_hi  = hh_lo + (size_t)NTOK * D_MODEL;
  short* y_lo  = y_hi  + (size_t)NTOK * D_INNER;
  short* wIh   = y_lo  + (size_t)NTOK * D_INNER;     // 8 layers in_proj hi
  short* wIl   = wIh + N_LAYER * WI;                 // 8 layers in_proj lo
  short* wOh   = wIl + N_LAYER * WI;                 // 8 layers out_proj hi
  short* wOl   = wOh + N_LAYER * WO;                 // 8 layers out_proj lo
  float* opart = xz;   // out_proj split-K partials reuse xz (z dead by then)

  // Hoisted weight splits: all layers at once (weights are layer-constant).
  split_kernel<<<2048, 256, 0, stream>>>(in_proj, wIh, wIl,
                                         (int)(N_LAYER * WI / 4));
  split_kernel<<<2048, 256, 0, stream>>>(out_proj, wOh, wOl,
                                         (int)(N_LAYER * WO / 4));

  for (int l = 0; l < N_LAYER; ++l) {
    ln_kernel<<<NTOK, 256, 0, stream>>>(x, pos, resid, opart, hh_hi, hh_lo,
        norm_w + l * D_MODEL, norm_b + l * D_MODEL, l == 0);

    dim3 g1(2 * D_INNER / 128, NTOK / 128, 1);
    gemm_bf16x3<<<g1, 256, 0, stream>>>(hh_hi, hh_lo, D_MODEL,
        wIh + l * WI, wIl + l * WI, D_MODEL, xz, NTOK, 2 * D_INNER, D_MODEL);

    int convtot = BATCH * (SEQLEN / CONV_TCH) * (D_INNER / 4);
    conv_silu_kernel<<<(convtot + 255) / 256, 256, 0, stream>>>(
        xz, conv_w + (size_t)l * D_INNER * D_CONV, conv_b + l * D_INNER, u);

    dim3 gxp(NTOK / 64, XP_KS);
    xproj_gemm<<<gxp, 256, 0, stream>>>(
        u, x_proj + (size_t)l * DBC_W * D_INNER, dbcp);
    reduce_dbc_kernel<<<(NTOK * DBC_W / 4 + 255) / 256, 256, 0, stream>>>(
        dbcp, dbc, NTOK * DBC_W / 4);

    const float* Al = A_log + (size_t)l * D_INNER * D_STATE;
    const float* dtwl = dt_w + (size_t)l * D_INNER * DT_RANK;
    const float* dtbl = dt_b + (size_t)l * D_INNER;
    int tot1 = BATCH * NC * D_INNER;
    scan_chunk1<<<tot1 / 256, 256, 0, stream>>>(
        dty, u, dbc, Al, dtwl, dtbl, Sbuf, dtsum);
    scan_combine<<<(BATCH * D_STATE * D_INNER + 255) / 256, 256, 0, stream>>>(
        Sbuf, dtsum, Al);
    scan_chunk2<<<tot1 / 256, 256, 0, stream>>>(
        dty, u, dbc, xz, Al, Dv + l * D_INNER, Sbuf, y_hi, y_lo);

    // out_proj split-K=4: partials into opart (reused xz); reduction fused
    // into next layer's ln_kernel / final_kernel.
    dim3 g2(D_MODEL / 128, NTOK / 128, OP_KS);
    gemm_bf16x3<<<g2, 256, 0, stream>>>(y_hi, y_lo, D_INNER,
        wOh + l * WO, wOl + l * WO, D_INNER, opart, NTOK, D_MODEL, D_INNER);
  }

  final_kernel<<<BATCH * rtn, 256, 0, stream>>>(
      opart, resid, normf_w, normf_b, dec_w, dec_b, (float*)d_out, rtn);
}